// Round 7
// baseline (435.061 us; speedup 1.0000x reference)
//
#include <hip/hip_runtime.h>
#include <hip/hip_bf16.h>

#define B_   2
#define S_   2048
#define E_   2048
#define QKV_ 3072
#define NH   16
#define NKV  4
#define HD   128

typedef __attribute__((ext_vector_type(8))) short bf16x8;
typedef __attribute__((ext_vector_type(4))) float f32x4;
typedef unsigned short u16;
typedef unsigned int   u32;

__device__ __forceinline__ float bf2f(u16 u) {
  union { u32 i; float f; } v; v.i = ((u32)u) << 16; return v.f;
}
__device__ __forceinline__ u16 f2bf(float f) {
  union { float f; u32 u; } v; v.f = f;
  return (u16)((v.u + 0x7FFFu + ((v.u >> 16) & 1u)) >> 16);
}
// packed RNE f32x2 -> bf16x2 (low = a)
__device__ __forceinline__ u32 pkbf(float a, float b) {
  __hip_bfloat162 h = __float22bfloat162_rn(float2{a, b});
  u32 r; __builtin_memcpy(&r, &h, 4); return r;
}
// 2^x via v_exp_f32
__device__ __forceinline__ float ex2(float x) { return __builtin_amdgcn_exp2f(x); }
__device__ __forceinline__ void load_lds16(const u16* g, u16* l) {
  __builtin_amdgcn_global_load_lds((const __attribute__((address_space(1))) void*)g,
                                   (__attribute__((address_space(3))) void*)l, 16, 0, 0);
}

// ---------------- fp32 -> bf16 bulk convert (n multiple of 4) ----------------
__global__ __launch_bounds__(256) void f2b_conv(const float* __restrict__ in,
                                                u16* __restrict__ out, int n4) {
  const int i = blockIdx.x * 256 + threadIdx.x;
  if (i >= n4) return;
  const float4 v = ((const float4*)in)[i];
  ushort4 o;
  o.x = f2bf(v.x); o.y = f2bf(v.y); o.z = f2bf(v.z); o.w = f2bf(v.w);
  ((ushort4*)out)[i] = o;
}

// ---------------- rope table: cos/sin[s*64+i] ----------------
__global__ __launch_bounds__(256) void rope_tab(float* __restrict__ c,
                                                float* __restrict__ s) {
  const int idx = blockIdx.x * 256 + threadIdx.x;  // 2048*64
  const int t = idx >> 6, i = idx & 63;
  const float invf = powf(10000.0f, -(float)i * (1.0f / 64.0f));
  float sn, cs;
  sincosf((float)t * invf, &sn, &cs);
  c[idx] = cs; s[idx] = sn;
}

// ---------------- GEMM: C[M,N] = A[M,K] * B[N,K]^T + bias[N] ----------------
template <int OUT_BF16>
__global__ __launch_bounds__(256) void gemm_bt(const u16* __restrict__ A,
                                               const u16* __restrict__ Bm,
                                               const float* __restrict__ bias,
                                               void* __restrict__ C,
                                               int M, int N, int K) {
  __shared__ u16 As[128 * 32];
  __shared__ u16 Bs[128 * 32];
  const int tid = threadIdx.x;
  const int wave = tid >> 6, lane = tid & 63;
  const int m0 = blockIdx.y * 128, n0 = blockIdx.x * 128;
  const int wm = (wave & 1) * 64, wn = (wave >> 1) * 64;
  const int L15 = lane & 15, Lq = lane >> 4;
  const int lrow = lane >> 2, lcol = (lane & 3) * 8;

  f32x4 acc[4][4] = {};

  for (int k0 = 0; k0 < K; k0 += 32) {
#pragma unroll
    for (int c = 0; c < 2; ++c) {
      const int chunk = c * 4 + wave;
      const int row = chunk * 16 + lrow;
      load_lds16(A  + (size_t)(m0 + row) * K + k0 + lcol, &As[chunk * 512 + lane * 8]);
      load_lds16(Bm + (size_t)(n0 + row) * K + k0 + lcol, &Bs[chunk * 512 + lane * 8]);
    }
    __syncthreads();
    bf16x8 af[4], bfr[4];
#pragma unroll
    for (int t = 0; t < 4; ++t) {
      af[t]  = *(const bf16x8*)&As[(wm + t * 16 + L15) * 32 + Lq * 8];
      bfr[t] = *(const bf16x8*)&Bs[(wn + t * 16 + L15) * 32 + Lq * 8];
    }
#pragma unroll
    for (int mt = 0; mt < 4; ++mt)
#pragma unroll
      for (int nt = 0; nt < 4; ++nt)
        acc[mt][nt] = __builtin_amdgcn_mfma_f32_16x16x32_bf16(af[mt], bfr[nt], acc[mt][nt], 0, 0, 0);
    __syncthreads();
  }

#pragma unroll
  for (int nt = 0; nt < 4; ++nt) {
    const int col = n0 + wn + nt * 16 + L15;
    const float bv = bias[col];
#pragma unroll
    for (int mt = 0; mt < 4; ++mt) {
#pragma unroll
      for (int r = 0; r < 4; ++r) {
        const int row = m0 + wm + mt * 16 + Lq * 4 + r;
        const float v = acc[mt][nt][r] + bv;
        if (OUT_BF16) ((u16*)C)[(size_t)row * N + col] = f2bf(v);
        else          ((float*)C)[(size_t)row * N + col] = v;
      }
    }
  }
}

// ------------- depthwise causal conv(4) + bias + RoPE + split/layout -------------
// q pre-scaled by log2(e)/sqrt(HD) (softmax uses exp2). v written ROW-major
// (coalesced) to vtmp; a separate transpose kernel produces v^T.
__global__ __launch_bounds__(256) void conv_rope(const u16* __restrict__ qkv,
                                                 const float* __restrict__ cw,
                                                 const float* __restrict__ cb,
                                                 const float* __restrict__ ct,
                                                 const float* __restrict__ st,
                                                 u16* __restrict__ qo,
                                                 u16* __restrict__ ko,
                                                 u16* __restrict__ vtmp) {
  const int bs = blockIdx.x;
  const int b = bs >> 11, s = bs & 2047;
  const int tid = threadIdx.x;

  auto conv2 = [&](int f, float& a0, float& a1) {
    a0 = cb[f]; a1 = cb[f + 1];
    const float4 w0 = *(const float4*)&cw[f * 4];
    const float4 w1 = *(const float4*)&cw[(f + 1) * 4];
    const float wa0[4] = {w0.x, w0.y, w0.z, w0.w};
    const float wa1[4] = {w1.x, w1.y, w1.z, w1.w};
#pragma unroll
    for (int d = 0; d < 4; ++d) {
      const int t = s - 3 + d;
      if (t >= 0) {
        const u32 pk = *(const u32*)&qkv[((size_t)b * S_ + t) * QKV_ + f];
        a0 += wa0[d] * bf2f((u16)pk);
        a1 += wa1[d] * bf2f((u16)(pk >> 16));
      }
    }
  };

  for (int p = tid; p < (NH + NKV) * 32; p += 256) {
    int f1, i; u16* outp; float scale;
    if (p < NH * 32) {
      const int h = p >> 5; i = (p & 31) * 2;
      f1 = h * HD + i;
      outp = qo + ((size_t)(b * NH + h) * S_ + s) * HD;
      scale = 0.08838834764831845f * 1.4426950408889634f;  // log2e/sqrt(128)
    } else {
      const int pk = p - NH * 32;
      const int h = pk >> 5; i = (pk & 31) * 2;
      f1 = NH * HD + h * HD + i;
      outp = ko + ((size_t)(b * NKV + h) * S_ + s) * HD;
      scale = 1.0f;
    }
    float x1a, x1b, x2a, x2b;
    conv2(f1, x1a, x1b);
    conv2(f1 + 64, x2a, x2b);
    const float2 cs = *(const float2*)&ct[s * 64 + i];
    const float2 sn = *(const float2*)&st[s * 64 + i];
    *(u32*)&outp[i]      = pkbf((x1a * cs.x - x2a * sn.x) * scale,
                                (x1b * cs.y - x2b * sn.y) * scale);
    *(u32*)&outp[i + 64] = pkbf((x2a * cs.x + x1a * sn.x) * scale,
                                (x2b * cs.y + x1b * sn.y) * scale);
  }
  {
    const int p = tid;
    const int h = p >> 6, d = (p & 63) * 2;
    const int f = (NH + NKV) * HD + h * HD + d;
    float v0, v1;
    conv2(f, v0, v1);
    *(u32*)&vtmp[((size_t)(b * NKV + h) * S_ + s) * HD + d] = pkbf(v0, v1);
  }
}

// ---------------- v (B,NKV,S,HD) -> v^T (B,NKV,HD,S), 64x64 LDS tiles ----------------
__global__ __launch_bounds__(256) void vtrans(const u16* __restrict__ vin,
                                              u16* __restrict__ vout) {
  __shared__ u16 t[64][72];
  const int bh = blockIdx.z;
  const int d0 = blockIdx.y * 64;
  const int s0 = blockIdx.x * 64;
  const u16* ip = vin + ((size_t)bh * S_ + s0) * HD + d0;
  const int r = threadIdx.x >> 4, c4 = (threadIdx.x & 15) * 4;
#pragma unroll
  for (int j = 0; j < 4; ++j) {
    const ushort4 v = *(const ushort4*)&ip[(size_t)(r + j * 16) * HD + c4];
    t[c4 + 0][r + j * 16] = v.x;
    t[c4 + 1][r + j * 16] = v.y;
    t[c4 + 2][r + j * 16] = v.z;
    t[c4 + 3][r + j * 16] = v.w;
  }
  __syncthreads();
  const int dl = threadIdx.x >> 2, sc = (threadIdx.x & 3) * 16;
  u16* op = vout + (size_t)bh * HD * S_ + (size_t)(d0 + dl) * S_ + s0 + sc;
  *(bf16x8*)op       = *(const bf16x8*)&t[dl][sc];
  *(bf16x8*)(op + 8) = *(const bf16x8*)&t[dl][sc + 8];
}

// ------------------------- flash attention (causal, GQA) -------------------------
// grid (8, B*NH); block i handles q-tiles qt=i and qt=15-i -> 34 balanced iters.
// LDS exactly 80 KB -> 2 blocks/CU (2 waves/SIMD). P swizzled at stride 64.
__global__ __launch_bounds__(256, 2) void attn(const u16* __restrict__ q,
                                               const u16* __restrict__ k,
                                               const u16* __restrict__ v,
                                               u16* __restrict__ ctx) {
  __shared__ u16 Ks[2][64 * 128];
  __shared__ u16 Vs[2][128 * 64];
  __shared__ u16 P[4][32 * 64];
  const int tid = threadIdx.x, wave = tid >> 6, lane = tid & 63;
  const int L15 = lane & 15, Lq = lane >> 4;
  const int bh = blockIdx.y;
  const int b = bh >> 4, h = bh & 15, hk = h >> 2;

  const u16* kb = k + (size_t)(b * NKV + hk) * S_ * HD;
  const u16* vb = v + (size_t)(b * NKV + hk) * HD * S_;

  const int rx = L15 & 7;
  int koff[4], voff[2], poff[2][2];
#pragma unroll
  for (int c = 0; c < 4; ++c) koff[c] = ((c * 4 + Lq) ^ rx) * 8;
#pragma unroll
  for (int kc = 0; kc < 2; ++kc) {
    voff[kc] = ((kc * 4 + Lq) ^ rx) * 8;
#pragma unroll
    for (int rt = 0; rt < 2; ++rt)
      poff[rt][kc] = (rt * 16 + L15) * 64 + ((kc * 4 + Lq) ^ rx) * 8;
  }

  const int ksl = tid >> 4, kcp = tid & 15;
  const int vsl = tid >> 3, vcp = tid & 7;

  for (int pass = 0; pass < 2; ++pass) {
    const int qt = pass ? (15 - blockIdx.x) : blockIdx.x;
    const int q0 = qt * 128;
    const int base = q0 + wave * 32;

    bf16x8 qf[2][4];
#pragma unroll
    for (int rt = 0; rt < 2; ++rt) {
      const u16* qp = q + ((size_t)bh * S_ + base + rt * 16 + L15) * HD + Lq * 8;
#pragma unroll
      for (int c = 0; c < 4; ++c) qf[rt][c] = *(const bf16x8*)(qp + c * 32);
    }

    f32x4 acc[2][8] = {};
    float m_i[2][4], l_i[2][4];
#pragma unroll
    for (int rt = 0; rt < 2; ++rt)
#pragma unroll
      for (int r = 0; r < 4; ++r) { m_i[rt][r] = -1e30f; l_i[rt][r] = 0.f; }

    const int ktmax = 2 * (qt + 1);

#pragma unroll
    for (int j = 0; j < 4; ++j) {
      const int krow = j * 16 + ksl;
      load_lds16(kb + (size_t)krow * HD + (kcp ^ (krow & 7)) * 8,
                 &Ks[0][(krow * 16 + kcp) * 8]);
      const int vrow = j * 32 + vsl;
      load_lds16(vb + (size_t)vrow * S_ + (vcp ^ (vrow & 7)) * 8,
                 &Vs[0][(vrow * 8 + vcp) * 8]);
    }
    __syncthreads();

    for (int kt = 0; kt < ktmax; ++kt) {
      const int k0 = kt * 64;
      const int cur = kt & 1;
      if (kt + 1 < ktmax) {
        const int kn = k0 + 64;
#pragma unroll
        for (int j = 0; j < 4; ++j) {
          const int krow = j * 16 + ksl;
          load_lds16(kb + (size_t)(kn + krow) * HD + (kcp ^ (krow & 7)) * 8,
                     &Ks[cur ^ 1][(krow * 16 + kcp) * 8]);
          const int vrow = j * 32 + vsl;
          load_lds16(vb + (size_t)vrow * S_ + kn + (vcp ^ (vrow & 7)) * 8,
                     &Vs[cur ^ 1][(vrow * 8 + vcp) * 8]);
        }
      }
      if (k0 <= base + 31) {
        // ---- QK^T ----
        f32x4 sc[2][4];
#pragma unroll
        for (int rt = 0; rt < 2; ++rt)
#pragma unroll
          for (int nt = 0; nt < 4; ++nt) sc[rt][nt] = f32x4{0.f, 0.f, 0.f, 0.f};
#pragma unroll
        for (int nt = 0; nt < 4; ++nt) {
#pragma unroll
          for (int c = 0; c < 4; ++c) {
            const bf16x8 kf = *(const bf16x8*)&Ks[cur][(nt * 16 + L15) * 128 + koff[c]];
#pragma unroll
            for (int rt = 0; rt < 2; ++rt)
              sc[rt][nt] = __builtin_amdgcn_mfma_f32_16x16x32_bf16(qf[rt][c], kf, sc[rt][nt], 0, 0, 0);
          }
        }
        if (k0 + 63 > base) {
#pragma unroll
          for (int rt = 0; rt < 2; ++rt)
#pragma unroll
            for (int nt = 0; nt < 4; ++nt) {
              const int col = k0 + nt * 16 + L15;
#pragma unroll
              for (int r = 0; r < 4; ++r) {
                const int row = base + rt * 16 + Lq * 4 + r;
                if (col > row) sc[rt][nt][r] = -1e30f;
              }
            }
        }
        // ---- online softmax (exp2 domain) ----
        float mloc[2][4];
        bool nm = false;
#pragma unroll
        for (int rt = 0; rt < 2; ++rt)
#pragma unroll
          for (int r = 0; r < 4; ++r) {
            float m = fmaxf(fmaxf(sc[rt][0][r], sc[rt][1][r]), fmaxf(sc[rt][2][r], sc[rt][3][r]));
            m = fmaxf(m, __shfl_xor(m, 1));
            m = fmaxf(m, __shfl_xor(m, 2));
            m = fmaxf(m, __shfl_xor(m, 4));
            m = fmaxf(m, __shfl_xor(m, 8));
            mloc[rt][r] = m;
            nm |= (m > m_i[rt][r]);
          }
        const bool anynew = (__ballot(nm) != 0ull);
        float rsum[2][4];
#pragma unroll
        for (int rt = 0; rt < 2; ++rt) {
          float mnew[4];
#pragma unroll
          for (int r = 0; r < 4; ++r) {
            mnew[r] = anynew ? fmaxf(m_i[rt][r], mloc[rt][r]) : m_i[rt][r];
            rsum[rt][r] = 0.f;
          }
          float pv[4][4];
#pragma unroll
          for (int nt = 0; nt < 4; ++nt)
#pragma unroll
            for (int r = 0; r < 4; ++r) {
              pv[nt][r] = ex2(sc[rt][nt][r] - mnew[r]);
              rsum[rt][r] += pv[nt][r];
            }
          // packed bf16 conversion + swizzled P store
#pragma unroll
          for (int nt = 0; nt < 4; ++nt) {
            const int cch = nt * 2 + (L15 >> 3), clo = L15 & 7;
#pragma unroll
            for (int rp = 0; rp < 2; ++rp) {
              const u32 pk = pkbf(pv[nt][rp * 2], pv[nt][rp * 2 + 1]);
              const int row0 = rt * 16 + Lq * 4 + rp * 2;
              P[wave][row0 * 64 + (((cch ^ (row0 & 7)) << 3) | clo)] = (u16)pk;
              const int row1 = row0 + 1;
              P[wave][row1 * 64 + (((cch ^ (row1 & 7)) << 3) | clo)] = (u16)(pk >> 16);
            }
          }
          if (anynew) {
            float alpha[4];
#pragma unroll
            for (int r = 0; r < 4; ++r) {
              alpha[r] = ex2(m_i[rt][r] - mnew[r]);
              m_i[rt][r] = mnew[r];
            }
#pragma unroll
            for (int dt = 0; dt < 8; ++dt)
#pragma unroll
              for (int r = 0; r < 4; ++r) acc[rt][dt][r] *= alpha[r];
#pragma unroll
            for (int r = 0; r < 4; ++r) l_i[rt][r] *= alpha[r];
          }
        }
#pragma unroll
        for (int rt = 0; rt < 2; ++rt)
#pragma unroll
          for (int r = 0; r < 4; ++r) {
            float s = rsum[rt][r];
            s += __shfl_xor(s, 1);
            s += __shfl_xor(s, 2);
            s += __shfl_xor(s, 4);
            s += __shfl_xor(s, 8);
            l_i[rt][r] += s;
          }
        // ---- PV ----
        bf16x8 pa[2][2];
#pragma unroll
        for (int rt = 0; rt < 2; ++rt)
#pragma unroll
          for (int kc = 0; kc < 2; ++kc)
            pa[rt][kc] = *(const bf16x8*)&P[wave][poff[rt][kc]];
#pragma unroll
        for (int dt = 0; dt < 8; ++dt)
#pragma unroll
          for (int kc = 0; kc < 2; ++kc) {
            const bf16x8 vf = *(const bf16x8*)&Vs[cur][(dt * 16 + L15) * 64 + voff[kc]];
#pragma unroll
            for (int rt = 0; rt < 2; ++rt)
              acc[rt][dt] = __builtin_amdgcn_mfma_f32_16x16x32_bf16(pa[rt][kc], vf, acc[rt][dt], 0, 0, 0);
          }
      }
      __syncthreads();
    }
    // ---- epilogue ----
#pragma unroll
    for (int rt = 0; rt < 2; ++rt) {
      float inv[4];
#pragma unroll
      for (int r = 0; r < 4; ++r) inv[r] = 1.f / l_i[rt][r];
      u16* cp = ctx + ((size_t)b * S_ + base + rt * 16) * (NH * HD) + h * HD;
#pragma unroll
      for (int dt = 0; dt < 8; ++dt)
#pragma unroll
        for (int rp = 0; rp < 2; ++rp) {
          const u32 pk = pkbf(acc[rt][dt][rp * 2] * inv[rp * 2],
                              acc[rt][dt][rp * 2 + 1] * inv[rp * 2 + 1]);
          cp[(size_t)(Lq * 4 + rp * 2) * (NH * HD) + dt * 16 + L15] = (u16)pk;
          cp[(size_t)(Lq * 4 + rp * 2 + 1) * (NH * HD) + dt * 16 + L15] = (u16)(pk >> 16);
        }
    }
  }
}

extern "C" void kernel_launch(void* const* d_in, const int* in_sizes, int n_in,
                              void* d_out, int out_size, void* d_ws, size_t ws_size,
                              hipStream_t stream) {
  const float* x     = (const float*)d_in[0];
  const float* W_in  = (const float*)d_in[1];
  const float* b_in  = (const float*)d_in[2];
  const float* cw    = (const float*)d_in[3];
  const float* cb    = (const float*)d_in[4];
  const float* W_out = (const float*)d_in[5];
  const float* b_out = (const float*)d_in[6];

  char* ws = (char*)d_ws;
  u16* xb   = (u16*)(ws);                    // 16777216 B (dead after gemm1)
  u16* wib  = (u16*)(ws + 16777216);         // 12582912 B (dead after gemm1)
  u16* wob  = (u16*)(ws + 29360128);         //  8388608 B
  u16* qkv  = (u16*)(ws + 37748736);         // 25165824 B
  u16* q_ws = (u16*)(ws + 62914560);         // 16777216 B
  u16* k_ws = (u16*)(ws + 79691776);         //  4194304 B
  u16* vt_ws= (u16*)(ws + 83886080);         //  4194304 B
  float* ctab = (float*)ws;                  // rope tables in dead xb region
  float* stab = (float*)(ws + 524288);
  u16* vtmp = wib;                           // v row-major, in dead wib region
  u16* ctx  = xb;                            // alias: xb dead after gemm1

  const int nx = B_ * S_ * E_ / 4, nwi = QKV_ * E_ / 4, nwo = E_ * NH * HD / 4;
  f2b_conv<<<dim3((nx  + 255) / 256), 256, 0, stream>>>(x,     xb,  nx);
  f2b_conv<<<dim3((nwi + 255) / 256), 256, 0, stream>>>(W_in,  wib, nwi);
  f2b_conv<<<dim3((nwo + 255) / 256), 256, 0, stream>>>(W_out, wob, nwo);

  gemm_bt<1><<<dim3(QKV_ / 128, (B_ * S_) / 128), 256, 0, stream>>>(
      xb, wib, b_in, (void*)qkv, B_ * S_, QKV_, E_);
  rope_tab<<<dim3(S_ * 64 / 256), 256, 0, stream>>>(ctab, stab);
  conv_rope<<<dim3(B_ * S_), 256, 0, stream>>>(qkv, cw, cb, ctab, stab, q_ws, k_ws, vtmp);
  vtrans<<<dim3(S_ / 64, HD / 64, B_ * NKV), 256, 0, stream>>>(vtmp, vt_ws);
  attn<<<dim3(8, B_ * NH), 256, 0, stream>>>(q_ws, k_ws, vt_ws, ctx);
  gemm_bt<0><<<dim3(E_ / 128, (B_ * S_) / 128), 256, 0, stream>>>(
      ctx, wob, b_out, d_out, B_ * S_, E_, NH * HD);
}

// Round 8
// 417.816 us; speedup vs baseline: 1.0413x; 1.0413x over previous
//
#include <hip/hip_runtime.h>
#include <hip/hip_bf16.h>

#define B_   2
#define S_   2048
#define E_   2048
#define QKV_ 3072
#define NH   16
#define NKV  4
#define HD   128
#define SL   16   // conv_rope strip length

typedef __attribute__((ext_vector_type(8))) short bf16x8;
typedef __attribute__((ext_vector_type(4))) float f32x4;
typedef unsigned short u16;
typedef unsigned int   u32;

__device__ __forceinline__ float bf2f(u16 u) {
  union { u32 i; float f; } v; v.i = ((u32)u) << 16; return v.f;
}
__device__ __forceinline__ u16 f2bf(float f) {
  union { float f; u32 u; } v; v.f = f;
  return (u16)((v.u + 0x7FFFu + ((v.u >> 16) & 1u)) >> 16);
}
__device__ __forceinline__ u32 pkbf(float a, float b) {
  __hip_bfloat162 h = __float22bfloat162_rn(float2{a, b});
  u32 r; __builtin_memcpy(&r, &h, 4); return r;
}
__device__ __forceinline__ float ex2(float x) { return __builtin_amdgcn_exp2f(x); }
__device__ __forceinline__ void load_lds16(const u16* g, u16* l) {
  __builtin_amdgcn_global_load_lds((const __attribute__((address_space(1))) void*)g,
                                   (__attribute__((address_space(3))) void*)l, 16, 0, 0);
}

// ---------------- fp32 -> bf16 bulk convert (n multiple of 4) ----------------
__global__ __launch_bounds__(256) void f2b_conv(const float* __restrict__ in,
                                                u16* __restrict__ out, int n4) {
  const int i = blockIdx.x * 256 + threadIdx.x;
  if (i >= n4) return;
  const float4 v = ((const float4*)in)[i];
  ushort4 o;
  o.x = f2bf(v.x); o.y = f2bf(v.y); o.z = f2bf(v.z); o.w = f2bf(v.w);
  ((ushort4*)out)[i] = o;
}

// ---------------- rope table: cos/sin[s*64+i] ----------------
__global__ __launch_bounds__(256) void rope_tab(float* __restrict__ c,
                                                float* __restrict__ s) {
  const int idx = blockIdx.x * 256 + threadIdx.x;  // 2048*64
  const int t = idx >> 6, i = idx & 63;
  const float invf = powf(10000.0f, -(float)i * (1.0f / 64.0f));
  float sn, cs;
  sincosf((float)t * invf, &sn, &cs);
  c[idx] = cs; s[idx] = sn;
}

// ---------------- GEMM: C[M,N] = A[M,K] * B[N,K]^T + bias[N] ----------------
template <int OUT_BF16>
__global__ __launch_bounds__(256) void gemm_bt(const u16* __restrict__ A,
                                               const u16* __restrict__ Bm,
                                               const float* __restrict__ bias,
                                               void* __restrict__ C,
                                               int M, int N, int K) {
  __shared__ u16 As[128 * 32];
  __shared__ u16 Bs[128 * 32];
  const int tid = threadIdx.x;
  const int wave = tid >> 6, lane = tid & 63;
  const int m0 = blockIdx.y * 128, n0 = blockIdx.x * 128;
  const int wm = (wave & 1) * 64, wn = (wave >> 1) * 64;
  const int L15 = lane & 15, Lq = lane >> 4;
  const int lrow = lane >> 2, lcol = (lane & 3) * 8;

  f32x4 acc[4][4] = {};

  for (int k0 = 0; k0 < K; k0 += 32) {
#pragma unroll
    for (int c = 0; c < 2; ++c) {
      const int chunk = c * 4 + wave;
      const int row = chunk * 16 + lrow;
      load_lds16(A  + (size_t)(m0 + row) * K + k0 + lcol, &As[chunk * 512 + lane * 8]);
      load_lds16(Bm + (size_t)(n0 + row) * K + k0 + lcol, &Bs[chunk * 512 + lane * 8]);
    }
    __syncthreads();
    bf16x8 af[4], bfr[4];
#pragma unroll
    for (int t = 0; t < 4; ++t) {
      af[t]  = *(const bf16x8*)&As[(wm + t * 16 + L15) * 32 + Lq * 8];
      bfr[t] = *(const bf16x8*)&Bs[(wn + t * 16 + L15) * 32 + Lq * 8];
    }
#pragma unroll
    for (int mt = 0; mt < 4; ++mt)
#pragma unroll
      for (int nt = 0; nt < 4; ++nt)
        acc[mt][nt] = __builtin_amdgcn_mfma_f32_16x16x32_bf16(af[mt], bfr[nt], acc[mt][nt], 0, 0, 0);
    __syncthreads();
  }

#pragma unroll
  for (int nt = 0; nt < 4; ++nt) {
    const int col = n0 + wn + nt * 16 + L15;
    const float bv = bias[col];
#pragma unroll
    for (int mt = 0; mt < 4; ++mt) {
#pragma unroll
      for (int r = 0; r < 4; ++r) {
        const int row = m0 + wm + mt * 16 + Lq * 4 + r;
        const float v = acc[mt][nt][r] + bv;
        if (OUT_BF16) ((u16*)C)[(size_t)row * N + col] = f2bf(v);
        else          ((float*)C)[(size_t)row * N + col] = v;
      }
    }
  }
}

// ------------- depthwise causal conv(4) + bias + RoPE, streaming over s -------------
// Each unit owns a feature-pair (and its rotary partner) and walks SL s-values,
// carrying the 3-tap conv window in registers: every qkv element loaded exactly
// once, coalesced. q pre-scaled by log2(e)/sqrt(HD); v written row-major.
__global__ __launch_bounds__(256) void conv_rope(const u16* __restrict__ qkv,
                                                 const float* __restrict__ cw,
                                                 const float* __restrict__ cb,
                                                 const float* __restrict__ ct,
                                                 const float* __restrict__ st,
                                                 u16* __restrict__ qo,
                                                 u16* __restrict__ ko,
                                                 u16* __restrict__ vtmp) {
  const int blk = blockIdx.x;                 // B * (S/SL)
  const int b = blk >> 7;                     // S/SL = 128
  const int s0 = (blk & 127) * SL;
  const u16* qb = qkv + (size_t)b * S_ * QKV_;

  for (int u = threadIdx.x; u < 896; u += 256) {
    if (u < 640) {
      // ---- rotary unit: features f1,f1+1 and f1+64,f1+65 ----
      const int hs = u >> 5, ip = u & 31, i = ip * 2;
      int f1; u16* outbase; float scale;
      if (hs < 16) {
        f1 = hs * HD + i;
        outbase = qo + (size_t)(b * NH + hs) * S_ * HD;
        scale = 0.08838834764831845f * 1.4426950408889634f;  // log2e/sqrt(128)
      } else {
        f1 = NH * HD + (hs - 16) * HD + i;
        outbase = ko + (size_t)(b * NKV + (hs - 16)) * S_ * HD;
        scale = 1.0f;
      }
      const int f2 = f1 + 64;
      const float4 wA0 = *(const float4*)&cw[f1 * 4];
      const float4 wA1 = *(const float4*)&cw[(f1 + 1) * 4];
      const float4 wB0 = *(const float4*)&cw[f2 * 4];
      const float4 wB1 = *(const float4*)&cw[(f2 + 1) * 4];
      const float cA0 = cb[f1], cA1 = cb[f1 + 1], cB0 = cb[f2], cB1 = cb[f2 + 1];
      float A0[3], A1[3], B0[3], B1[3];
#pragma unroll
      for (int j = 0; j < 3; ++j) {
        const int t = s0 - 3 + j;
        if (t >= 0) {
          const u32 pa = *(const u32*)&qb[(size_t)t * QKV_ + f1];
          const u32 pb = *(const u32*)&qb[(size_t)t * QKV_ + f2];
          A0[j] = bf2f((u16)pa); A1[j] = bf2f((u16)(pa >> 16));
          B0[j] = bf2f((u16)pb); B1[j] = bf2f((u16)(pb >> 16));
        } else { A0[j] = A1[j] = B0[j] = B1[j] = 0.f; }
      }
      for (int s = s0; s < s0 + SL; ++s) {
        const u32 pa = *(const u32*)&qb[(size_t)s * QKV_ + f1];
        const u32 pb = *(const u32*)&qb[(size_t)s * QKV_ + f2];
        const float nA0 = bf2f((u16)pa), nA1 = bf2f((u16)(pa >> 16));
        const float nB0 = bf2f((u16)pb), nB1 = bf2f((u16)(pb >> 16));
        const float x1a = cA0 + wA0.x * A0[0] + wA0.y * A0[1] + wA0.z * A0[2] + wA0.w * nA0;
        const float x1b = cA1 + wA1.x * A1[0] + wA1.y * A1[1] + wA1.z * A1[2] + wA1.w * nA1;
        const float x2a = cB0 + wB0.x * B0[0] + wB0.y * B0[1] + wB0.z * B0[2] + wB0.w * nB0;
        const float x2b = cB1 + wB1.x * B1[0] + wB1.y * B1[1] + wB1.z * B1[2] + wB1.w * nB1;
        const float2 cs = *(const float2*)&ct[s * 64 + i];
        const float2 sn = *(const float2*)&st[s * 64 + i];
        u16* outp = outbase + (size_t)s * HD;
        *(u32*)&outp[i]      = pkbf((x1a * cs.x - x2a * sn.x) * scale,
                                    (x1b * cs.y - x2b * sn.y) * scale);
        *(u32*)&outp[i + 64] = pkbf((x2a * cs.x + x1a * sn.x) * scale,
                                    (x2b * cs.y + x1b * sn.y) * scale);
        A0[0] = A0[1]; A0[1] = A0[2]; A0[2] = nA0;
        A1[0] = A1[1]; A1[1] = A1[2]; A1[2] = nA1;
        B0[0] = B0[1]; B0[1] = B0[2]; B0[2] = nB0;
        B1[0] = B1[1]; B1[1] = B1[2]; B1[2] = nB1;
      }
    } else {
      // ---- v unit: features f, f+1 ----
      const int vu = u - 640, h = vu >> 6, d = (vu & 63) * 2;
      const int f = (NH + NKV) * HD + h * HD + d;
      const float4 w0 = *(const float4*)&cw[f * 4];
      const float4 w1 = *(const float4*)&cw[(f + 1) * 4];
      const float c0 = cb[f], c1 = cb[f + 1];
      float V0[3], V1[3];
#pragma unroll
      for (int j = 0; j < 3; ++j) {
        const int t = s0 - 3 + j;
        if (t >= 0) {
          const u32 p = *(const u32*)&qb[(size_t)t * QKV_ + f];
          V0[j] = bf2f((u16)p); V1[j] = bf2f((u16)(p >> 16));
        } else { V0[j] = V1[j] = 0.f; }
      }
      u16* vrow = vtmp + (size_t)(b * NKV + h) * S_ * HD + d;
      for (int s = s0; s < s0 + SL; ++s) {
        const u32 p = *(const u32*)&qb[(size_t)s * QKV_ + f];
        const float n0 = bf2f((u16)p), n1 = bf2f((u16)(p >> 16));
        const float v0 = c0 + w0.x * V0[0] + w0.y * V0[1] + w0.z * V0[2] + w0.w * n0;
        const float v1 = c1 + w1.x * V1[0] + w1.y * V1[1] + w1.z * V1[2] + w1.w * n1;
        *(u32*)&vrow[(size_t)s * HD] = pkbf(v0, v1);
        V0[0] = V0[1]; V0[1] = V0[2]; V0[2] = n0;
        V1[0] = V1[1]; V1[1] = V1[2]; V1[2] = n1;
      }
    }
  }
}

// ---------------- v (B,NKV,S,HD) -> v^T (B,NKV,HD,S), 64x64 LDS tiles ----------------
__global__ __launch_bounds__(256) void vtrans(const u16* __restrict__ vin,
                                              u16* __restrict__ vout) {
  __shared__ u16 t[64][72];
  const int bh = blockIdx.z;
  const int d0 = blockIdx.y * 64;
  const int s0 = blockIdx.x * 64;
  const u16* ip = vin + ((size_t)bh * S_ + s0) * HD + d0;
  const int r = threadIdx.x >> 4, c4 = (threadIdx.x & 15) * 4;
#pragma unroll
  for (int j = 0; j < 4; ++j) {
    const ushort4 v = *(const ushort4*)&ip[(size_t)(r + j * 16) * HD + c4];
    t[c4 + 0][r + j * 16] = v.x;
    t[c4 + 1][r + j * 16] = v.y;
    t[c4 + 2][r + j * 16] = v.z;
    t[c4 + 3][r + j * 16] = v.w;
  }
  __syncthreads();
  const int dl = threadIdx.x >> 2, sc = (threadIdx.x & 3) * 16;
  u16* op = vout + (size_t)bh * HD * S_ + (size_t)(d0 + dl) * S_ + s0 + sc;
  *(bf16x8*)op       = *(const bf16x8*)&t[dl][sc];
  *(bf16x8*)(op + 8) = *(const bf16x8*)&t[dl][sc + 8];
}

// ------------------------- flash attention (causal, GQA) -------------------------
// grid (8, B*NH); block i handles q-tiles qt=i and qt=15-i -> 34 balanced iters.
// LDS 64 KB (K double-buffered, V single-buffered, P) -> 2 blocks/CU.
// Per iter: issue V(kt)+K(kt+1) DMA -> QK+softmax (covers DMA) -> barrier ->
// PV -> barrier (V buffer free).
__global__ __launch_bounds__(256, 2) void attn(const u16* __restrict__ q,
                                               const u16* __restrict__ k,
                                               const u16* __restrict__ v,
                                               u16* __restrict__ ctx) {
  __shared__ u16 Ks[2][64 * 128];
  __shared__ u16 Vs[128 * 64];
  __shared__ u16 P[4][32 * 64];
  const int tid = threadIdx.x, wave = tid >> 6, lane = tid & 63;
  const int L15 = lane & 15, Lq = lane >> 4;
  const int bh = blockIdx.y;
  const int b = bh >> 4, h = bh & 15, hk = h >> 2;

  const u16* kb = k + (size_t)(b * NKV + hk) * S_ * HD;
  const u16* vb = v + (size_t)(b * NKV + hk) * HD * S_;

  const int rx = L15 & 7;
  int koff[4], voff[2], poff[2][2];
#pragma unroll
  for (int c = 0; c < 4; ++c) koff[c] = ((c * 4 + Lq) ^ rx) * 8;
#pragma unroll
  for (int kc = 0; kc < 2; ++kc) {
    voff[kc] = ((kc * 4 + Lq) ^ rx) * 8;
#pragma unroll
    for (int rt = 0; rt < 2; ++rt)
      poff[rt][kc] = (rt * 16 + L15) * 64 + ((kc * 4 + Lq) ^ rx) * 8;
  }

  const int ksl = tid >> 4, kcp = tid & 15;
  const int vsl = tid >> 3, vcp = tid & 7;

  for (int pass = 0; pass < 2; ++pass) {
    const int qt = pass ? (15 - blockIdx.x) : blockIdx.x;
    const int q0 = qt * 128;
    const int base = q0 + wave * 32;

    bf16x8 qf[2][4];
#pragma unroll
    for (int rt = 0; rt < 2; ++rt) {
      const u16* qp = q + ((size_t)bh * S_ + base + rt * 16 + L15) * HD + Lq * 8;
#pragma unroll
      for (int c = 0; c < 4; ++c) qf[rt][c] = *(const bf16x8*)(qp + c * 32);
    }

    f32x4 acc[2][8] = {};
    float m_i[2][4], l_i[2][4];
#pragma unroll
    for (int rt = 0; rt < 2; ++rt)
#pragma unroll
      for (int r = 0; r < 4; ++r) { m_i[rt][r] = -1e30f; l_i[rt][r] = 0.f; }

    const int ktmax = 2 * (qt + 1);

    // preamble: stage K(0) and V(0)
#pragma unroll
    for (int j = 0; j < 4; ++j) {
      const int krow = j * 16 + ksl;
      load_lds16(kb + (size_t)krow * HD + (kcp ^ (krow & 7)) * 8,
                 &Ks[0][(krow * 16 + kcp) * 8]);
      const int vrow = j * 32 + vsl;
      load_lds16(vb + (size_t)vrow * S_ + (vcp ^ (vrow & 7)) * 8,
                 &Vs[(vrow * 8 + vcp) * 8]);
    }
    __syncthreads();

    for (int kt = 0; kt < ktmax; ++kt) {
      const int k0 = kt * 64;
      const int cur = kt & 1;
      if (kt > 0) {  // V(kt): buffer free since end-barrier of kt-1
#pragma unroll
        for (int j = 0; j < 4; ++j) {
          const int vrow = j * 32 + vsl;
          load_lds16(vb + (size_t)vrow * S_ + k0 + (vcp ^ (vrow & 7)) * 8,
                     &Vs[(vrow * 8 + vcp) * 8]);
        }
      }
      if (kt + 1 < ktmax) {  // K(kt+1) into other K buffer
        const int kn = k0 + 64;
#pragma unroll
        for (int j = 0; j < 4; ++j) {
          const int krow = j * 16 + ksl;
          load_lds16(kb + (size_t)(kn + krow) * HD + (kcp ^ (krow & 7)) * 8,
                     &Ks[cur ^ 1][(krow * 16 + kcp) * 8]);
        }
      }
      const bool active = (k0 <= base + 31);
      f32x4 sc[2][4];
      if (active) {
        // ---- QK^T from Ks[cur] (staged in iter kt-1, drained by prior barrier) ----
#pragma unroll
        for (int rt = 0; rt < 2; ++rt)
#pragma unroll
          for (int nt = 0; nt < 4; ++nt) sc[rt][nt] = f32x4{0.f, 0.f, 0.f, 0.f};
#pragma unroll
        for (int nt = 0; nt < 4; ++nt) {
#pragma unroll
          for (int c = 0; c < 4; ++c) {
            const bf16x8 kf = *(const bf16x8*)&Ks[cur][(nt * 16 + L15) * 128 + koff[c]];
#pragma unroll
            for (int rt = 0; rt < 2; ++rt)
              sc[rt][nt] = __builtin_amdgcn_mfma_f32_16x16x32_bf16(qf[rt][c], kf, sc[rt][nt], 0, 0, 0);
          }
        }
        if (k0 + 63 > base) {
#pragma unroll
          for (int rt = 0; rt < 2; ++rt)
#pragma unroll
            for (int nt = 0; nt < 4; ++nt) {
              const int col = k0 + nt * 16 + L15;
#pragma unroll
              for (int r = 0; r < 4; ++r) {
                const int row = base + rt * 16 + Lq * 4 + r;
                if (col > row) sc[rt][nt][r] = -1e30f;
              }
            }
        }
        // ---- online softmax (exp2 domain) ----
        float mloc[2][4];
        bool nm = false;
#pragma unroll
        for (int rt = 0; rt < 2; ++rt)
#pragma unroll
          for (int r = 0; r < 4; ++r) {
            float m = fmaxf(fmaxf(sc[rt][0][r], sc[rt][1][r]), fmaxf(sc[rt][2][r], sc[rt][3][r]));
            m = fmaxf(m, __shfl_xor(m, 1));
            m = fmaxf(m, __shfl_xor(m, 2));
            m = fmaxf(m, __shfl_xor(m, 4));
            m = fmaxf(m, __shfl_xor(m, 8));
            mloc[rt][r] = m;
            nm |= (m > m_i[rt][r]);
          }
        const bool anynew = (__ballot(nm) != 0ull);
        float rsum[2][4];
#pragma unroll
        for (int rt = 0; rt < 2; ++rt) {
          float mnew[4];
#pragma unroll
          for (int r = 0; r < 4; ++r) {
            mnew[r] = anynew ? fmaxf(m_i[rt][r], mloc[rt][r]) : m_i[rt][r];
            rsum[rt][r] = 0.f;
          }
          float pv[4][4];
#pragma unroll
          for (int nt = 0; nt < 4; ++nt)
#pragma unroll
            for (int r = 0; r < 4; ++r) {
              pv[nt][r] = ex2(sc[rt][nt][r] - mnew[r]);
              rsum[rt][r] += pv[nt][r];
            }
#pragma unroll
          for (int nt = 0; nt < 4; ++nt) {
            const int cch = nt * 2 + (L15 >> 3), clo = L15 & 7;
#pragma unroll
            for (int rp = 0; rp < 2; ++rp) {
              const u32 pk = pkbf(pv[nt][rp * 2], pv[nt][rp * 2 + 1]);
              const int row0 = rt * 16 + Lq * 4 + rp * 2;
              P[wave][row0 * 64 + (((cch ^ (row0 & 7)) << 3) | clo)] = (u16)pk;
              const int row1 = row0 + 1;
              P[wave][row1 * 64 + (((cch ^ (row1 & 7)) << 3) | clo)] = (u16)(pk >> 16);
            }
          }
          if (anynew) {
            float alpha[4];
#pragma unroll
            for (int r = 0; r < 4; ++r) {
              alpha[r] = ex2(m_i[rt][r] - mnew[r]);
              m_i[rt][r] = mnew[r];
            }
#pragma unroll
            for (int dt = 0; dt < 8; ++dt)
#pragma unroll
              for (int r = 0; r < 4; ++r) acc[rt][dt][r] *= alpha[r];
#pragma unroll
            for (int r = 0; r < 4; ++r) l_i[rt][r] *= alpha[r];
          }
        }
#pragma unroll
        for (int rt = 0; rt < 2; ++rt)
#pragma unroll
          for (int r = 0; r < 4; ++r) {
            float s = rsum[rt][r];
            s += __shfl_xor(s, 1);
            s += __shfl_xor(s, 2);
            s += __shfl_xor(s, 4);
            s += __shfl_xor(s, 8);
            l_i[rt][r] += s;
          }
      }
      __syncthreads();  // M: V(kt)+K(kt+1) DMA drained; all waves synced
      if (active) {
        // ---- PV from Vs ----
        bf16x8 pa[2][2];
#pragma unroll
        for (int rt = 0; rt < 2; ++rt)
#pragma unroll
          for (int kc = 0; kc < 2; ++kc)
            pa[rt][kc] = *(const bf16x8*)&P[wave][poff[rt][kc]];
#pragma unroll
        for (int dt = 0; dt < 8; ++dt)
#pragma unroll
          for (int kc = 0; kc < 2; ++kc) {
            const bf16x8 vf = *(const bf16x8*)&Vs[(dt * 16 + L15) * 64 + voff[kc]];
#pragma unroll
            for (int rt = 0; rt < 2; ++rt)
              acc[rt][dt] = __builtin_amdgcn_mfma_f32_16x16x32_bf16(pa[rt][kc], vf, acc[rt][dt], 0, 0, 0);
          }
      }
      __syncthreads();  // E: V reads done before next iter's V DMA
    }
    // ---- epilogue ----
#pragma unroll
    for (int rt = 0; rt < 2; ++rt) {
      float inv[4];
#pragma unroll
      for (int r = 0; r < 4; ++r) inv[r] = 1.f / l_i[rt][r];
      u16* cp = ctx + ((size_t)b * S_ + base + rt * 16) * (NH * HD) + h * HD;
#pragma unroll
      for (int dt = 0; dt < 8; ++dt)
#pragma unroll
        for (int rp = 0; rp < 2; ++rp) {
          const u32 pk = pkbf(acc[rt][dt][rp * 2] * inv[rp * 2],
                              acc[rt][dt][rp * 2 + 1] * inv[rp * 2 + 1]);
          cp[(size_t)(Lq * 4 + rp * 2) * (NH * HD) + dt * 16 + L15] = (u16)pk;
          cp[(size_t)(Lq * 4 + rp * 2 + 1) * (NH * HD) + dt * 16 + L15] = (u16)(pk >> 16);
        }
    }
  }
}

extern "C" void kernel_launch(void* const* d_in, const int* in_sizes, int n_in,
                              void* d_out, int out_size, void* d_ws, size_t ws_size,
                              hipStream_t stream) {
  const float* x     = (const float*)d_in[0];
  const float* W_in  = (const float*)d_in[1];
  const float* b_in  = (const float*)d_in[2];
  const float* cw    = (const float*)d_in[3];
  const float* cb    = (const float*)d_in[4];
  const float* W_out = (const float*)d_in[5];
  const float* b_out = (const float*)d_in[6];

  char* ws = (char*)d_ws;
  u16* xb   = (u16*)(ws);                    // 16777216 B (dead after gemm1)
  u16* wib  = (u16*)(ws + 16777216);         // 12582912 B (dead after gemm1)
  u16* wob  = (u16*)(ws + 29360128);         //  8388608 B
  u16* qkv  = (u16*)(ws + 37748736);         // 25165824 B
  u16* q_ws = (u16*)(ws + 62914560);         // 16777216 B
  u16* k_ws = (u16*)(ws + 79691776);         //  4194304 B
  u16* vt_ws= (u16*)(ws + 83886080);         //  4194304 B
  float* ctab = (float*)ws;                  // rope tables in dead xb region
  float* stab = (float*)(ws + 524288);
  u16* vtmp = wib;                           // v row-major, in dead wib region
  u16* ctx  = xb;                            // alias: xb dead after gemm1

  const int nx = B_ * S_ * E_ / 4, nwi = QKV_ * E_ / 4, nwo = E_ * NH * HD / 4;
  f2b_conv<<<dim3((nx  + 255) / 256), 256, 0, stream>>>(x,     xb,  nx);
  f2b_conv<<<dim3((nwi + 255) / 256), 256, 0, stream>>>(W_in,  wib, nwi);
  f2b_conv<<<dim3((nwo + 255) / 256), 256, 0, stream>>>(W_out, wob, nwo);

  gemm_bt<1><<<dim3(QKV_ / 128, (B_ * S_) / 128), 256, 0, stream>>>(
      xb, wib, b_in, (void*)qkv, B_ * S_, QKV_, E_);
  rope_tab<<<dim3(S_ * 64 / 256), 256, 0, stream>>>(ctab, stab);
  conv_rope<<<dim3(B_ * (S_ / SL)), 256, 0, stream>>>(qkv, cw, cb, ctab, stab, q_ws, k_ws, vtmp);
  vtrans<<<dim3(S_ / 64, HD / 64, B_ * NKV), 256, 0, stream>>>(vtmp, vt_ws);
  attn<<<dim3(8, B_ * NH), 256, 0, stream>>>(q_ws, k_ws, vt_ws, ctx);
  gemm_bt<0><<<dim3(E_ / 128, (B_ * S_) / 128), 256, 0, stream>>>(
      ctx, wob, b_out, d_out, B_ * S_, E_, NH * HD);
}